// Round 1
// 121.997 us; speedup vs baseline: 1.1030x; 1.1030x over previous
//
#include <hip/hip_runtime.h>
#include <math.h>

#define NB 4096
#define ND 1024
#define SCALEF 20.0f

typedef __bf16 bf16_t;
typedef bf16_t bf16x4 __attribute__((ext_vector_type(4)));
typedef bf16_t bf16x8 __attribute__((ext_vector_type(8)));
typedef float floatx4 __attribute__((ext_vector_type(4)));

__device__ __forceinline__ void load16_to_lds(const void* g, void* l) {
    __builtin_amdgcn_global_load_lds(
        (const __attribute__((address_space(1))) void*)g,
        (__attribute__((address_space(3))) void*)l, 16, 0, 0);
}

// ---------------------------------------------------------------------------
// Kernel 1: fused L2-normalize + fp32->bf16 convert. One wave per row.
// Also zeroes rowsum[] (A rows) and out[0].
// ---------------------------------------------------------------------------
__global__ __launch_bounds__(256) void mnrl_norm_cvt(
    const float* __restrict__ A, const float* __restrict__ P,
    bf16_t* __restrict__ Abf, bf16_t* __restrict__ Pbf,
    float* __restrict__ rowsum, float* __restrict__ out) {
    if (blockIdx.x == 0 && threadIdx.x == 0) out[0] = 0.0f;
    int row = blockIdx.x * 4 + (threadIdx.x >> 6);  // 0..8191
    int lane = threadIdx.x & 63;
    bool is_a = row < NB;
    const float* src = is_a ? (A + (size_t)row * ND)
                            : (P + (size_t)(row - NB) * ND);
    bf16_t* dst = is_a ? (Abf + (size_t)row * ND)
                       : (Pbf + (size_t)(row - NB) * ND);

    float4 v[4];
    float ss = 0.0f;
#pragma unroll
    for (int i = 0; i < 4; ++i) {
        v[i] = ((const float4*)src)[i * 64 + lane];
        ss += v[i].x * v[i].x + v[i].y * v[i].y + v[i].z * v[i].z + v[i].w * v[i].w;
    }
#pragma unroll
    for (int off = 32; off > 0; off >>= 1) ss += __shfl_xor(ss, off, 64);
    float inv = 1.0f / fmaxf(sqrtf(ss), 1e-8f);
#pragma unroll
    for (int i = 0; i < 4; ++i) {
        bf16x4 w;
        w[0] = (bf16_t)(v[i].x * inv);
        w[1] = (bf16_t)(v[i].y * inv);
        w[2] = (bf16_t)(v[i].z * inv);
        w[3] = (bf16_t)(v[i].w * inv);
        ((bf16x4*)dst)[i * 64 + lane] = w;
    }
    if (is_a && lane == 0) rowsum[row] = 0.0f;
}

// ---------------------------------------------------------------------------
// Kernel 2: 256x256-tile bf16 MFMA GEMM, 8 waves (2Mx4N), BK=32,
// ring-4 LDS double^2 buffer, lookahead-3 global_load_lds prefetch with
// counted vmcnt(8) (never drained to 0 in main loop), raw s_barrier,
// setprio around the MFMA cluster. Fused exp-sum (fixed shift 20) + diag.
//
// LDS per K-tile: A 256 rows x 32 bf16 (64 B/row), XOR-swizzled:
//   16B chunk q of row r lives at slot q ^ ((r>>1)&3). Fetch side pre-swizzles
//   the per-lane global address (gload_lds dest is linear: base + lane*16).
// ---------------------------------------------------------------------------
__global__ __launch_bounds__(512, 2) void mnrl_gemm_lse(
    const bf16_t* __restrict__ Abf, const bf16_t* __restrict__ Pbf,
    float* __restrict__ rowsum, float* __restrict__ diag) {
    __shared__ __align__(16) bf16_t lds_a[4][256 * 32];
    __shared__ __align__(16) bf16_t lds_b[4][256 * 32];

    // XCD-aware swizzle (256 blocks, 8 XCDs -> 32 contiguous tiles per XCD:
    // 2 full tile_m rows each -> A panel L2-resident per XCD).
    int bid = blockIdx.x;
    int swz = (bid & 7) * 32 + (bid >> 3);
    int tile_m = swz >> 4;
    int tile_n = swz & 15;

    int t = threadIdx.x;
    int lane = t & 63;
    int w = t >> 6;           // 0..7
    int wm = w >> 2;          // 0..1  (128-row half)
    int wn = w & 3;           // 0..3  (64-col quarter)
    int quad = lane >> 4, l16 = lane & 15;

    const bf16_t* Abase = Abf + (size_t)tile_m * 256 * ND;
    const bf16_t* Pbase = Pbf + (size_t)tile_n * 256 * ND;

    // Staging: per wave, 2 issues per matrix; issue covers 16 rows (1 KiB).
    // Lane l -> row (l>>2), LDS slot (l&3); fetch global chunk (l&3)^((l>>3)&3)
    // so that slot s of row r holds chunk s ^ ((r>>1)&3).
    int srow = lane >> 2;
    int chunk = (lane & 3) ^ ((lane >> 3) & 3);
    const bf16_t* srcA0 = Abase + (size_t)(w * 32 + srow) * ND + chunk * 8;
    const bf16_t* srcA1 = srcA0 + (size_t)16 * ND;
    const bf16_t* srcP0 = Pbase + (size_t)(w * 32 + srow) * ND + chunk * 8;
    const bf16_t* srcP1 = srcP0 + (size_t)16 * ND;
    const int dst0 = w * 1024;        // (w*32)*32 elems
    const int dst1 = w * 1024 + 512;  // (w*32+16)*32 elems

    // Fragment read offsets (elements). Row stride 32 elems (64 B).
    int key = (l16 >> 1) & 3;
    int slot8 = (quad ^ key) * 8;
    int offA[8], offB[4];
#pragma unroll
    for (int mt = 0; mt < 8; ++mt)
        offA[mt] = (wm * 128 + mt * 16 + l16) * 32 + slot8;
#pragma unroll
    for (int nt = 0; nt < 4; ++nt)
        offB[nt] = (wn * 64 + nt * 16 + l16) * 32 + slot8;

    floatx4 acc[8][4];
#pragma unroll
    for (int mt = 0; mt < 8; ++mt)
#pragma unroll
        for (int nt = 0; nt < 4; ++nt) acc[mt][nt] = (floatx4){0.f, 0.f, 0.f, 0.f};

#define STAGE(KT)                                                   \
    {                                                               \
        int koff_ = (KT) * 32;                                      \
        int b_ = (KT) & 3;                                          \
        load16_to_lds(srcA0 + koff_, &lds_a[b_][dst0]);             \
        load16_to_lds(srcA1 + koff_, &lds_a[b_][dst1]);             \
        load16_to_lds(srcP0 + koff_, &lds_b[b_][dst0]);             \
        load16_to_lds(srcP1 + koff_, &lds_b[b_][dst1]);             \
    }

#define K_BODY(KT, DOSTAGE)                                                  \
    {                                                                        \
        int b_ = (KT) & 3;                                                   \
        if (DOSTAGE) STAGE((KT) + 3);                                        \
        bf16x8 af[8], bv[4];                                                 \
        _Pragma("unroll") for (int mt = 0; mt < 8; ++mt)                     \
            af[mt] = *(const bf16x8*)&lds_a[b_][offA[mt]];                   \
        _Pragma("unroll") for (int nt = 0; nt < 4; ++nt)                     \
            bv[nt] = *(const bf16x8*)&lds_b[b_][offB[nt]];                   \
        __builtin_amdgcn_s_setprio(1);                                       \
        _Pragma("unroll") for (int mt = 0; mt < 8; ++mt)                     \
            _Pragma("unroll") for (int nt = 0; nt < 4; ++nt)                 \
                acc[mt][nt] = __builtin_amdgcn_mfma_f32_16x16x32_bf16(       \
                    af[mt], bv[nt], acc[mt][nt], 0, 0, 0);                   \
        __builtin_amdgcn_s_setprio(0);                                       \
    }

    // Prologue: 3 K-tiles in flight (12 loads/thread).
    STAGE(0);
    STAGE(1);
    STAGE(2);

    // Main loop: 29 steps with staging. At top of step kt the loads newer
    // than kt's are kt+1's and kt+2's (8/thread) -> vmcnt(8) forces kt's 4
    // (oldest) complete; barrier makes them visible to all waves.
    for (int kt = 0; kt < 29; ++kt) {
        asm volatile("s_waitcnt vmcnt(8)" ::: "memory");
        __builtin_amdgcn_s_barrier();
        asm volatile("" ::: "memory");
        K_BODY(kt, 1);
    }
    // Tail: kt=29 (newer: 30,31 -> 8), kt=30 (newer: 31 -> 4), kt=31 (0).
    asm volatile("s_waitcnt vmcnt(8)" ::: "memory");
    __builtin_amdgcn_s_barrier();
    asm volatile("" ::: "memory");
    K_BODY(29, 0);
    asm volatile("s_waitcnt vmcnt(4)" ::: "memory");
    __builtin_amdgcn_s_barrier();
    asm volatile("" ::: "memory");
    K_BODY(30, 0);
    asm volatile("s_waitcnt vmcnt(0)" ::: "memory");
    __builtin_amdgcn_s_barrier();
    asm volatile("" ::: "memory");
    K_BODY(31, 0);

#undef K_BODY
#undef STAGE

    // Epilogue. C/D layout: col = l16, row = quad*4 + r.
    bool diag_block = (tile_m == tile_n);
    float psum[8][4];
#pragma unroll
    for (int mt = 0; mt < 8; ++mt)
#pragma unroll
        for (int r = 0; r < 4; ++r) psum[mt][r] = 0.0f;

#pragma unroll
    for (int mt = 0; mt < 8; ++mt)
#pragma unroll
        for (int nt = 0; nt < 4; ++nt)
#pragma unroll
            for (int r = 0; r < 4; ++r) {
                float sc = SCALEF * acc[mt][nt][r];
                psum[mt][r] += __expf(sc - SCALEF);  // scores in [-20,20]
                if (diag_block) {
                    int rt = wm * 128 + mt * 16 + quad * 4 + r;
                    int ct = wn * 64 + nt * 16 + l16;
                    if (rt == ct) diag[tile_m * 256 + rt] = sc;
                }
            }

    // Cross-l16 reduce, then cross-wn reduce in LDS -> 1 atomic per row.
    // Safe to reuse lds_a[0] (buf 0 last read at kt=28, >=3 barriers ago).
    float* part = (float*)&lds_a[0][0];  // [4 wn][256 rows]
#pragma unroll
    for (int mt = 0; mt < 8; ++mt)
#pragma unroll
        for (int r = 0; r < 4; ++r) {
            float v = psum[mt][r];
            v += __shfl_xor(v, 1, 64);
            v += __shfl_xor(v, 2, 64);
            v += __shfl_xor(v, 4, 64);
            v += __shfl_xor(v, 8, 64);
            if (l16 == 0) part[wn * 256 + wm * 128 + mt * 16 + quad * 4 + r] = v;
        }
    __syncthreads();
    if (t < 256) {
        float s = part[t] + part[256 + t] + part[512 + t] + part[768 + t];
        atomicAdd(&rowsum[tile_m * 256 + t], s);
    }
}

// ---------------------------------------------------------------------------
// Kernel 3: loss = mean(log(rowsum) + 20 - diag). 16 blocks, atomic merge.
// ---------------------------------------------------------------------------
__global__ __launch_bounds__(256) void mnrl_finalize(const float* __restrict__ rowsum,
                                                     const float* __restrict__ diag,
                                                     float* __restrict__ out) {
    int t = threadIdx.x;
    int i = blockIdx.x * 256 + t;  // 16*256 = 4096
    float local = (logf(rowsum[i]) + SCALEF) - diag[i];
#pragma unroll
    for (int off = 32; off > 0; off >>= 1) local += __shfl_down(local, off, 64);
    __shared__ float sred[4];
    if ((t & 63) == 0) sred[t >> 6] = local;
    __syncthreads();
    if (t == 0)
        atomicAdd(out, (sred[0] + sred[1] + sred[2] + sred[3]) * (1.0f / (float)NB));
}

// ---------------------------------------------------------------------------
extern "C" void kernel_launch(void* const* d_in, const int* in_sizes, int n_in,
                              void* d_out, int out_size, void* d_ws, size_t ws_size,
                              hipStream_t stream) {
    const float* A = (const float*)d_in[0];
    const float* P = (const float*)d_in[1];

    bf16_t* Abf = (bf16_t*)d_ws;                        // 8 MiB
    bf16_t* Pbf = Abf + (size_t)NB * ND;                // 8 MiB
    float* rowsum = (float*)(Pbf + (size_t)NB * ND);    // 16 KiB (zeroed in cvt)
    float* diag = rowsum + NB;                          // 16 KiB

    mnrl_norm_cvt<<<2 * NB / 4, 256, 0, stream>>>(A, P, Abf, Pbf, rowsum,
                                                  (float*)d_out);
    mnrl_gemm_lse<<<16 * 16, 512, 0, stream>>>(Abf, Pbf, rowsum, diag);
    mnrl_finalize<<<16, 256, 0, stream>>>(rowsum, diag, (float*)d_out);
}